// Round 2
// 1965.820 us; speedup vs baseline: 1.2310x; 1.2310x over previous
//
#include <hip/hip_runtime.h>
#include <hip/hip_bf16.h>

using bf16 = __hip_bfloat16;
typedef __bf16 bf16x8v __attribute__((ext_vector_type(8)));
typedef __bf16 bf16x4v __attribute__((ext_vector_type(4)));
typedef float f32x4v __attribute__((ext_vector_type(4)));

#define EMBED 1024
#define FF_DIM 4096
#define NTOK 4096          // BATCH * SEQ
#define SEQL 2048
#define HD 64
#define WBAND 46           // ceil(sqrt(2048))
#define LN_EPS 1e-5f

// ---------------------------------------------------------------------------
// Input-dtype detection (robust): fp32 tensors have random mantissa bits in
// the low halfword (sane-bf16-exponent rate ~20%); bf16 tensors have a real
// N(0,1) bf16 there (rate ~100%). flag: 1 = bf16 inputs, 0 = fp32 inputs.
// ---------------------------------------------------------------------------
__global__ __launch_bounds__(256) void detect_dtype(
    const unsigned int* __restrict__ xw, int* __restrict__ flag)
{
  __shared__ int votes[256];
  int v = 0;
#pragma unroll
  for (int j = 0; j < 4; j++) {
    unsigned int w = xw[1 + threadIdx.x * 4 + j];
    unsigned int e = (w >> 7) & 0xFFu;          // low halfword's bf16 exponent
    v += (e == 0u || (e >= 0x58u && e <= 0x88u)) ? 1 : 0;
  }
  votes[threadIdx.x] = v;
  __syncthreads();
  if (threadIdx.x == 0) {
    int s = 0;
    for (int i = 0; i < 256; i++) s += votes[i];
    *flag = (s > 512) ? 1 : 0;
  }
}

// generic param cast -> bf16 internal copy (biases / LN gains), flag-branched
__global__ __launch_bounds__(256) void cast_param(
    const void* __restrict__ src, bf16* __restrict__ dst, int n,
    const int* __restrict__ dflag)
{
  const int is_bf16 = *dflag;
  for (int i = blockIdx.x * 256 + threadIdx.x; i < n; i += gridDim.x * 256)
    dst[i] = is_bf16 ? ((const bf16*)src)[i] : (bf16)(((const float*)src)[i]);
}

// x -> fp32 residual stream + bf16 activation copy, flag-branched
__global__ __launch_bounds__(256) void cast_in(
    const void* __restrict__ x, float* __restrict__ xf,
    bf16* __restrict__ xb, int n, const int* __restrict__ dflag)
{
  const int is_bf16 = *dflag;
  const int i = blockIdx.x * 256 + threadIdx.x;
  if (i < n) {
    float v = is_bf16 ? (float)((const bf16*)x)[i] : ((const float*)x)[i];
    xf[i] = v;
    xb[i] = (bf16)v;
  }
}

// ---------------------------------------------------------------------------
// NT GEMM: C[M,N] = A[M,K] @ W[N,K]^T + bias[N].
// A: bf16 internal. W: raw d_in weights (fp32 or bf16 per flag; converted to
// bf16 during staging). f32 accumulate. 128x128 tile, BK=32, 256 thr
// (4 waves x 4x4 MFMA 16x16x32 bf16). Verified layouts (m89/m91):
//  A-frag m=lane&15,k=(lane>>4)*8+j; B-frag n=lane&15,k=(lane>>4)*8+j;
//  C/D col(n)=lane&15, row(m)=(lane>>4)*4+reg.
// EPI: 0 = bf16 out + bias, 1 = bf16 out + bias + relu
// ---------------------------------------------------------------------------
template<int EPI>
__global__ __launch_bounds__(256) void gemm_nt(
    const bf16* __restrict__ A, const void* __restrict__ Wv, size_t woff,
    const bf16* __restrict__ bias, bf16* __restrict__ C,
    int M, int N, int K, const int* __restrict__ dflag)
{
  __shared__ __align__(16) bf16 lA[128 * 32];
  __shared__ __align__(16) bf16 lB[128 * 32];

  const int is_bf16 = *dflag;
  const int tid  = threadIdx.x;
  const int wave = tid >> 6;
  const int lane = tid & 63;
  const int row0 = blockIdx.x * 128;
  const int col0 = blockIdx.y * 128;
  const int wr0  = (wave >> 1) * 64;
  const int wc0  = (wave & 1) * 64;

  f32x4v acc[4][4];
#pragma unroll
  for (int i = 0; i < 4; i++)
#pragma unroll
    for (int j = 0; j < 4; j++) acc[i][j] = (f32x4v){0.f, 0.f, 0.f, 0.f};

  // staging map: lane -> row = wave*16 + lane/4, kchunk = (lane&3)*8 (8 elems);
  // second pass rows +64. LDS idx = row*32 + kchunk = wave*512 + lane*8.
  const int srow = wave * 16 + (lane >> 2);
  const int skc  = (lane & 3) * 8;
  const bf16*  Ag   = A + (size_t)(row0 + srow) * K + skc;
  const size_t bidx = woff + (size_t)(col0 + srow) * K + skc;   // element index
  bf16* lAp = lA + wave * 512 + lane * 8;
  bf16* lBp = lB + wave * 512 + lane * 8;

  const int fr = lane & 15;
  const int q8 = (lane >> 4) * 8;

  for (int k0 = 0; k0 < K; k0 += 32) {
    bf16x8v va0 = *reinterpret_cast<const bf16x8v*>(Ag + k0);
    bf16x8v va1 = *reinterpret_cast<const bf16x8v*>(Ag + (size_t)64 * K + k0);
    bf16x8v vb0, vb1;
    if (is_bf16) {
      const bf16* Wb = (const bf16*)Wv + bidx + k0;
      vb0 = *reinterpret_cast<const bf16x8v*>(Wb);
      vb1 = *reinterpret_cast<const bf16x8v*>(Wb + (size_t)64 * K);
    } else {
      const float* Wf = (const float*)Wv + bidx + k0;
      f32x4v a0 = *reinterpret_cast<const f32x4v*>(Wf);
      f32x4v a1 = *reinterpret_cast<const f32x4v*>(Wf + 4);
      f32x4v b0 = *reinterpret_cast<const f32x4v*>(Wf + (size_t)64 * K);
      f32x4v b1 = *reinterpret_cast<const f32x4v*>(Wf + (size_t)64 * K + 4);
#pragma unroll
      for (int j = 0; j < 4; j++) {
        vb0[j]     = (__bf16)a0[j];
        vb0[j + 4] = (__bf16)a1[j];
        vb1[j]     = (__bf16)b0[j];
        vb1[j + 4] = (__bf16)b1[j];
      }
    }
    __syncthreads();                         // WAR: previous iter's readers done
    *reinterpret_cast<bf16x8v*>(lAp)        = va0;
    *reinterpret_cast<bf16x8v*>(lAp + 2048) = va1;
    *reinterpret_cast<bf16x8v*>(lBp)        = vb0;
    *reinterpret_cast<bf16x8v*>(lBp + 2048) = vb1;
    __syncthreads();                         // staging visible

    bf16x8v af[4], bfv[4];
#pragma unroll
    for (int i = 0; i < 4; i++)
      af[i] = *reinterpret_cast<const bf16x8v*>(&lA[(wr0 + i * 16 + fr) * 32 + q8]);
#pragma unroll
    for (int j = 0; j < 4; j++)
      bfv[j] = *reinterpret_cast<const bf16x8v*>(&lB[(wc0 + j * 16 + fr) * 32 + q8]);
#pragma unroll
    for (int i = 0; i < 4; i++)
#pragma unroll
      for (int j = 0; j < 4; j++)
        acc[i][j] = __builtin_amdgcn_mfma_f32_16x16x32_bf16(af[i], bfv[j], acc[i][j], 0, 0, 0);
  }

  const int quad = (lane >> 4) * 4;
#pragma unroll
  for (int j = 0; j < 4; j++) {
    const int col = col0 + wc0 + j * 16 + fr;
    const float bv = (float)bias[col];
#pragma unroll
    for (int i = 0; i < 4; i++) {
      const int r0 = row0 + wr0 + i * 16 + quad;
#pragma unroll
      for (int r = 0; r < 4; r++) {
        float v = acc[i][j][r] + bv;
        if (EPI == 1) v = fmaxf(v, 0.f);
        C[(size_t)(r0 + r) * N + col] = (bf16)v;
      }
    }
  }
}

// ---------------------------------------------------------------------------
// Band-sparse attention, MFMA version. One block = 32 query rows of one
// (b,h); band span <= 124, padded to 128 keys (K/V zero-filled past L).
// MASKING: both |s-t|<=WBAND AND c<L are required. The c<L check is NOT
// redundant at the tail blocks: when thi clamps to SEQL-1, phantom columns
// c>=L have t=tlo+c numerically within the band of late rows (e.g. s=2047,
// t=2048) and their zero-filled K gives score 0, which would otherwise
// inflate the softmax denominator (round-1 failure, absmax 0.54).
//
// QK^T: M=32(q) N=128(key) K=64(d), 16 tiles of 16x16x32 (2 k-steps), 4 per
// wave. PV: M=32(q) N=64(d) K=128(key), needs B[n=d][k=key] = V^T, so V is
// staged transposed. All LDS tiles XOR-swizzled (elem ^= (row&7)<<3; f32
// score tile (row&7)<<2) so ds_read_b128 fragment reads sit at the 2-way /
// bandwidth floor (G4: row-major [*][64/128] tiles are otherwise 16-32-way).
// O may alias Q: the block's Q reads are staged to LDS before any O write,
// and blocks touch disjoint (rows x head-cols) slices.
// ---------------------------------------------------------------------------
#define SKI(t, d)  ((((t) * 64) + (d)) ^ (((t) & 7) << 3))   // sQf / sKf (64-wide)
#define SVI(d, t)  ((((d) * 128) + (t)) ^ (((d) & 7) << 3))  // sVtf (128-wide)
#define SPI(q, c)  ((((q) * 128) + (c)) ^ (((q) & 7) << 3))  // sPf
#define SSI(q, c)  ((((q) * 128) + (c)) ^ (((q) & 7) << 2))  // sSf (f32)

__global__ __launch_bounds__(256) void attn_band(
    const bf16* __restrict__ Q, const bf16* __restrict__ Kp,
    const bf16* __restrict__ Vp, bf16* __restrict__ O)
{
  const int sblk = blockIdx.x;
  const int bh   = blockIdx.y;
  const int b    = bh >> 4;
  const int h    = bh & 15;
  const int s0   = sblk * 32;
  int tlo = s0 - WBAND;       if (tlo < 0) tlo = 0;
  int thi = s0 + 31 + WBAND;  if (thi > SEQL - 1) thi = SEQL - 1;
  const int L = thi - tlo + 1;           // 78..124

  __shared__ __align__(16) bf16  sQf[32 * 64];
  __shared__ __align__(16) bf16  sKf[128 * 64];
  __shared__ __align__(16) bf16  sVtf[64 * 128];
  __shared__ __align__(16) float sSf[32 * 128];
  __shared__ __align__(16) bf16  sPf[32 * 128];
  __shared__ float red1[32][8];
  __shared__ float red2[32][8];
  __shared__ float sInv[32];

  const int tid  = threadIdx.x;
  const int wave = tid >> 6;
  const int lane = tid & 63;
  const size_t base = ((size_t)b * SEQL) * EMBED + (size_t)h * HD;

  bf16x8v vz;
#pragma unroll
  for (int j = 0; j < 8; j++) vz[j] = (__bf16)0.f;

  // --- stage Q (32x64): one bf16x8 per thread
  {
    const int sl = tid >> 3, d0 = (tid & 7) * 8;
    *reinterpret_cast<bf16x8v*>(&sQf[SKI(sl, d0)]) =
        *reinterpret_cast<const bf16x8v*>(&Q[base + (size_t)(s0 + sl) * EMBED + d0]);
  }
  // --- stage K (128x64), zero-padded rows >= L
  for (int i = tid; i < 128 * 8; i += 256) {
    const int tl = i >> 3, d0 = (i & 7) * 8;
    bf16x8v v = vz;
    if (tl < L)
      v = *reinterpret_cast<const bf16x8v*>(&Kp[base + (size_t)(tlo + tl) * EMBED + d0]);
    *reinterpret_cast<bf16x8v*>(&sKf[SKI(tl, d0)]) = v;
  }
  // --- stage V transposed (d-major rows): lane-consecutive tl keeps the
  // scalar LDS column-writes 2-way (conflict floor); global is 16B/lane.
  for (int i = tid; i < 128 * 8; i += 256) {
    const int tl = i & 127, d0 = ((i >> 7) & 7) * 8;
    bf16x8v v = vz;
    if (tl < L)
      v = *reinterpret_cast<const bf16x8v*>(&Vp[base + (size_t)(tlo + tl) * EMBED + d0]);
#pragma unroll
    for (int j = 0; j < 8; j++)
      sVtf[SVI(d0 + j, tl)] = reinterpret_cast<const bf16*>(&v)[j];
  }
  __syncthreads();

  const int fr   = lane & 15;
  const int q8   = (lane >> 4) * 8;
  const int quad = (lane >> 4) * 4;

  // --- QK^T: wave w owns n-tiles {2w, 2w+1} x m-tiles {0,1}
  {
    f32x4v acc[2][2];
#pragma unroll
    for (int mi = 0; mi < 2; mi++)
#pragma unroll
      for (int nj = 0; nj < 2; nj++) acc[mi][nj] = (f32x4v){0.f, 0.f, 0.f, 0.f};
#pragma unroll
    for (int ks = 0; ks < 2; ks++) {
      bf16x8v a0 = *reinterpret_cast<const bf16x8v*>(&sQf[SKI(fr,      ks * 32 + q8)]);
      bf16x8v a1 = *reinterpret_cast<const bf16x8v*>(&sQf[SKI(16 + fr, ks * 32 + q8)]);
      bf16x8v b0 = *reinterpret_cast<const bf16x8v*>(&sKf[SKI((wave * 2    ) * 16 + fr, ks * 32 + q8)]);
      bf16x8v b1 = *reinterpret_cast<const bf16x8v*>(&sKf[SKI((wave * 2 + 1) * 16 + fr, ks * 32 + q8)]);
      acc[0][0] = __builtin_amdgcn_mfma_f32_16x16x32_bf16(a0, b0, acc[0][0], 0, 0, 0);
      acc[0][1] = __builtin_amdgcn_mfma_f32_16x16x32_bf16(a0, b1, acc[0][1], 0, 0, 0);
      acc[1][0] = __builtin_amdgcn_mfma_f32_16x16x32_bf16(a1, b0, acc[1][0], 0, 0, 0);
      acc[1][1] = __builtin_amdgcn_mfma_f32_16x16x32_bf16(a1, b1, acc[1][1], 0, 0, 0);
    }
    // mask + scale + store scores; needs BOTH the band check and c < L
    // (phantom tail columns pass the band check at clamped-thi blocks)
#pragma unroll
    for (int nj = 0; nj < 2; nj++) {
      const int c = (wave * 2 + nj) * 16 + fr;
      const int t = tlo + c;
      const bool cvalid = (c < L);
#pragma unroll
      for (int mi = 0; mi < 2; mi++) {
#pragma unroll
        for (int r = 0; r < 4; r++) {
          const int row = mi * 16 + quad + r;
          int dd = (s0 + row) - t; if (dd < 0) dd = -dd;
          sSf[SSI(row, c)] = (cvalid && dd <= WBAND) ? acc[mi][nj][r] * 0.125f
                                                     : -1e30f;
        }
      }
    }
  }
  __syncthreads();

  // --- softmax over 128 cols, 8 partitions per row (row = tid&31)
  const int sl   = tid & 31;
  const int part = tid >> 5;
  float pmax = -1e30f;
#pragma unroll
  for (int k = 0; k < 16; k++) pmax = fmaxf(pmax, sSf[SSI(sl, part + 8 * k)]);
  red1[sl][part] = pmax;
  __syncthreads();
  float rmax = red1[sl][0];
#pragma unroll
  for (int p = 1; p < 8; p++) rmax = fmaxf(rmax, red1[sl][p]);

  float psum = 0.f;
#pragma unroll
  for (int k = 0; k < 16; k++) {
    const int c = part + 8 * k;
    float e = __expf(sSf[SSI(sl, c)] - rmax);   // masked/padded -> exactly 0
    sPf[SPI(sl, c)] = (bf16)e;
    psum += e;
  }
  red2[sl][part] = psum;
  __syncthreads();
  float rsum = 0.f;
#pragma unroll
  for (int p = 0; p < 8; p++) rsum += red2[sl][p];
  if (part == 0) sInv[sl] = 1.f / rsum;
  __syncthreads();                              // sPf + sInv ready

  // --- PV: O[32,64] = P[32,128] @ V. wave w: m-tile w>>1, n-tiles (w&1)*2+{0,1}
  {
    const int mi = wave >> 1;
    const int nb = (wave & 1) * 2;
    f32x4v acc[2];
    acc[0] = (f32x4v){0.f, 0.f, 0.f, 0.f};
    acc[1] = (f32x4v){0.f, 0.f, 0.f, 0.f};
#pragma unroll
    for (int ks = 0; ks < 4; ks++) {
      bf16x8v a  = *reinterpret_cast<const bf16x8v*>(&sPf[SPI(mi * 16 + fr, ks * 32 + q8)]);
      bf16x8v b0 = *reinterpret_cast<const bf16x8v*>(&sVtf[SVI((nb    ) * 16 + fr, ks * 32 + q8)]);
      bf16x8v b1 = *reinterpret_cast<const bf16x8v*>(&sVtf[SVI((nb + 1) * 16 + fr, ks * 32 + q8)]);
      acc[0] = __builtin_amdgcn_mfma_f32_16x16x32_bf16(a, b0, acc[0], 0, 0, 0);
      acc[1] = __builtin_amdgcn_mfma_f32_16x16x32_bf16(a, b1, acc[1], 0, 0, 0);
    }
#pragma unroll
    for (int nj = 0; nj < 2; nj++) {
      const int d = (nb + nj) * 16 + fr;
#pragma unroll
      for (int r = 0; r < 4; r++) {
        const int row = mi * 16 + quad + r;
        O[base + (size_t)(s0 + row) * EMBED + d] = (bf16)(acc[nj][r] * sInv[row]);
      }
    }
  }
}

// ---------------------------------------------------------------------------
// Fused residual add + LayerNorm. fp32 residual in/out (xin may == xf_out),
// bf16 GEMM-branch input y, bf16 activation out. Optional final output:
// dtype keyed off dflag (fp32 world -> float*, bf16 world -> bf16*).
// ---------------------------------------------------------------------------
__global__ __launch_bounds__(256) void resid_ln(
    const float* xin, const bf16* __restrict__ y,
    const bf16* __restrict__ g, const bf16* __restrict__ be,
    float* xf_out, bf16* __restrict__ xb_out,
    void* __restrict__ final_out, const int* __restrict__ dflag)
{
  __shared__ float red1[4];
  __shared__ float red2[4];
  const int row = blockIdx.x;
  const int tid = threadIdx.x;
  const size_t base = (size_t)row * EMBED + (size_t)tid * 4;

  f32x4v  xv = *reinterpret_cast<const f32x4v*>(xin + base);
  bf16x4v yv = *reinterpret_cast<const bf16x4v*>(y + base);
  float v[4];
#pragma unroll
  for (int j = 0; j < 4; j++) v[j] = xv[j] + (float)yv[j];

  float s = v[0] + v[1] + v[2] + v[3];
#pragma unroll
  for (int off = 32; off > 0; off >>= 1) s += __shfl_down(s, off, 64);
  if ((tid & 63) == 0) red1[tid >> 6] = s;
  __syncthreads();
  const float mu = (red1[0] + red1[1] + red1[2] + red1[3]) * (1.f / EMBED);

  float sq = 0.f;
#pragma unroll
  for (int j = 0; j < 4; j++) { const float d = v[j] - mu; sq += d * d; }
#pragma unroll
  for (int off = 32; off > 0; off >>= 1) sq += __shfl_down(sq, off, 64);
  if ((tid & 63) == 0) red2[tid >> 6] = sq;
  __syncthreads();
  const float rstd = rsqrtf((red2[0] + red2[1] + red2[2] + red2[3]) * (1.f / EMBED) + LN_EPS);

  bf16x4v gv = *reinterpret_cast<const bf16x4v*>(g + (size_t)tid * 4);
  bf16x4v bv = *reinterpret_cast<const bf16x4v*>(be + (size_t)tid * 4);
  f32x4v of;
  bf16x4v ov;
#pragma unroll
  for (int j = 0; j < 4; j++) {
    of[j] = (v[j] - mu) * rstd * (float)gv[j] + (float)bv[j];
    ov[j] = (__bf16)of[j];
  }
  *reinterpret_cast<f32x4v*>(xf_out + base) = of;
  *reinterpret_cast<bf16x4v*>(xb_out + base) = ov;
  if (final_out) {
    if (*dflag)
      *reinterpret_cast<bf16x4v*>((bf16*)final_out + base) = ov;
    else
      *reinterpret_cast<f32x4v*>((float*)final_out + base) = of;
  }
}

// ---------------------------------------------------------------------------
// ws layout (65 MB peak, liveness-verified):
//  [0,4K) flag | [4K,~112K) bf16 param copies
//  [ 1,17) xf fp32 residual | [17,25) xb bf16 activation
//  [25,33) q (=ao alias)    | [33,41) kk | [41,49) vv
//  [25,57) hh 32MB (aliases q/kk/vv + free [49,57); all dead at FF1)
//  [57,65) y bf16 GEMM out  (disjoint from hh: FF2 reads hh, writes y)
// ---------------------------------------------------------------------------
extern "C" void kernel_launch(void* const* d_in, const int* in_sizes, int n_in,
                              void* d_out, int out_size, void* d_ws, size_t ws_size,
                              hipStream_t stream)
{
  char* ws = (char*)d_ws;
  const size_t MB = 1024 * 1024;
  int*   flag = (int*)ws;
  bf16*  pp   = (bf16*)(ws + 4096);
  float* xf   = (float*)(ws + 1 * MB);
  bf16*  xb   = (bf16*)(ws + 17 * MB);
  bf16*  q    = (bf16*)(ws + 25 * MB);
  bf16*  kk   = (bf16*)(ws + 33 * MB);
  bf16*  vv   = (bf16*)(ws + 41 * MB);
  bf16*  ao   = q;
  bf16*  hh   = (bf16*)(ws + 25 * MB);     // 32 MB
  bf16*  y    = (bf16*)(ws + 57 * MB);

  // bf16 param-copy element offsets within pp
  bf16* pbq = pp;            bf16* pbk = pp + 4096;  bf16* pbv = pp + 8192;
  bf16* pbo = pp + 12288;    bf16* pb1 = pp + 16384; bf16* pb2 = pp + 32768;
  bf16* pg1 = pp + 36864;    bf16* pe1 = pp + 40960;
  bf16* pg2 = pp + 45056;    bf16* pe2 = pp + 49152;

  detect_dtype<<<1, 256, 0, stream>>>((const unsigned int*)d_in[0], flag);

  cast_param<<<16, 256, 0, stream>>>(d_in[2],  pbq, 4096,  flag);
  cast_param<<<16, 256, 0, stream>>>(d_in[4],  pbk, 4096,  flag);
  cast_param<<<16, 256, 0, stream>>>(d_in[6],  pbv, 4096,  flag);
  cast_param<<<16, 256, 0, stream>>>(d_in[8],  pbo, 4096,  flag);
  cast_param<<<64, 256, 0, stream>>>(d_in[10], pb1, 16384, flag);
  cast_param<<<16, 256, 0, stream>>>(d_in[12], pb2, 4096,  flag);
  cast_param<<<16, 256, 0, stream>>>(d_in[13], pg1, 4096,  flag);
  cast_param<<<16, 256, 0, stream>>>(d_in[14], pe1, 4096,  flag);
  cast_param<<<16, 256, 0, stream>>>(d_in[15], pg2, 4096,  flag);
  cast_param<<<16, 256, 0, stream>>>(d_in[16], pe2, 4096,  flag);

  cast_in<<<dim3((NTOK * EMBED) / 256), 256, 0, stream>>>(
      d_in[0], xf, xb, NTOK * EMBED, flag);

  for (int l = 0; l < 4; l++) {
    const size_t wEE = (size_t)l * EMBED * EMBED;
    const size_t wFE = (size_t)l * FF_DIM * EMBED;

    gemm_nt<0><<<dim3(32, 8),  256, 0, stream>>>(xb, d_in[1], wEE, pbq + l * 1024, q,  NTOK, EMBED, EMBED, flag);
    gemm_nt<0><<<dim3(32, 8),  256, 0, stream>>>(xb, d_in[3], wEE, pbk + l * 1024, kk, NTOK, EMBED, EMBED, flag);
    gemm_nt<0><<<dim3(32, 8),  256, 0, stream>>>(xb, d_in[5], wEE, pbv + l * 1024, vv, NTOK, EMBED, EMBED, flag);
    attn_band<<<dim3(SEQL / 32, 32), 256, 0, stream>>>(q, kk, vv, ao);
    gemm_nt<0><<<dim3(32, 8),  256, 0, stream>>>(ao, d_in[7], wEE, pbo + l * 1024, y, NTOK, EMBED, EMBED, flag);
    resid_ln<<<dim3(NTOK), 256, 0, stream>>>(xf, y, pg1 + l * 1024, pe1 + l * 1024, xf, xb, nullptr, flag);
    gemm_nt<1><<<dim3(32, 32), 256, 0, stream>>>(xb, d_in[9], wFE, pb1 + l * 4096, hh, NTOK, FF_DIM, EMBED, flag);
    gemm_nt<0><<<dim3(32, 8),  256, 0, stream>>>(hh, d_in[11], wFE, pb2 + l * 1024, y, NTOK, EMBED, FF_DIM, flag);
    resid_ln<<<dim3(NTOK), 256, 0, stream>>>(xf, y, pg2 + l * 1024, pe2 + l * 1024, xf, xb,
                                             l == 3 ? d_out : nullptr, flag);
  }
}

// Round 3
// 1491.289 us; speedup vs baseline: 1.6227x; 1.3182x over previous
//
#include <hip/hip_runtime.h>
#include <hip/hip_bf16.h>

using bf16 = __hip_bfloat16;
typedef __bf16 bf16x8v __attribute__((ext_vector_type(8)));
typedef __bf16 bf16x4v __attribute__((ext_vector_type(4)));
typedef float f32x4v __attribute__((ext_vector_type(4)));

#define EMBED 1024
#define FF_DIM 4096
#define NTOK 4096          // BATCH * SEQ
#define SEQL 2048
#define HD 64
#define WBAND 46           // ceil(sqrt(2048))
#define LN_EPS 1e-5f

// ---------------------------------------------------------------------------
// Input-dtype detection (robust): fp32 tensors have random mantissa bits in
// the low halfword (sane-bf16-exponent rate ~20%); bf16 tensors have a real
// N(0,1) bf16 there (rate ~100%). flag: 1 = bf16 inputs, 0 = fp32 inputs.
// ---------------------------------------------------------------------------
__global__ __launch_bounds__(256) void detect_dtype(
    const unsigned int* __restrict__ xw, int* __restrict__ flag)
{
  __shared__ int votes[256];
  int v = 0;
#pragma unroll
  for (int j = 0; j < 4; j++) {
    unsigned int w = xw[1 + threadIdx.x * 4 + j];
    unsigned int e = (w >> 7) & 0xFFu;          // low halfword's bf16 exponent
    v += (e == 0u || (e >= 0x58u && e <= 0x88u)) ? 1 : 0;
  }
  votes[threadIdx.x] = v;
  __syncthreads();
  if (threadIdx.x == 0) {
    int s = 0;
    for (int i = 0; i < 256; i++) s += votes[i];
    *flag = (s > 512) ? 1 : 0;
  }
}

// generic param cast -> bf16 internal copy (biases / LN gains), flag-branched
__global__ __launch_bounds__(256) void cast_param(
    const void* __restrict__ src, bf16* __restrict__ dst, int n,
    const int* __restrict__ dflag)
{
  const int is_bf16 = *dflag;
  for (int i = blockIdx.x * 256 + threadIdx.x; i < n; i += gridDim.x * 256)
    dst[i] = is_bf16 ? ((const bf16*)src)[i] : (bf16)(((const float*)src)[i]);
}

// x -> fp32 residual stream + bf16 activation copy, flag-branched
__global__ __launch_bounds__(256) void cast_in(
    const void* __restrict__ x, float* __restrict__ xf,
    bf16* __restrict__ xb, int n, const int* __restrict__ dflag)
{
  const int is_bf16 = *dflag;
  const int i = blockIdx.x * 256 + threadIdx.x;
  if (i < n) {
    float v = is_bf16 ? (float)((const bf16*)x)[i] : ((const float*)x)[i];
    xf[i] = v;
    xb[i] = (bf16)v;
  }
}

// ---------------------------------------------------------------------------
// NT GEMM core: C[128 x BN block] = A[M,K] @ W[N,K]^T + bias[N].
// A bf16 internal; W raw (fp32 or bf16 per flag, converted at commit time).
// 2-PHASE PREFETCH (T3-minimum): iter t+1's global loads are issued right
// after the staging barrier, consumed at t+1's commit -> HBM/L2 latency
// hides under ds_read+MFMA instead of being exposed between the barriers
// (round-2 profile: 1 block/CU, MfmaUtil 9%, all pipes idle = latency).
// The fp32->bf16 convert happens at COMMIT (not issue) so the prefetch
// doesn't force an early vmcnt wait.
// BN=128: 4 waves x acc[4][4]; BN=64: 4 waves x acc[4][2] (half-width tile
// to double the grid for N=1024 outputs). EPI: 1 = relu.
// Verified MFMA layouts (m89/m91): A/B-frag row=lane&15,k=(lane>>4)*8+j;
// C/D col=lane&15, row=(lane>>4)*4+reg.
// ---------------------------------------------------------------------------
template<int EPI, int BN>
__device__ __forceinline__ void gemm_core(
    const bf16* __restrict__ A, const void* __restrict__ Wp, size_t woff,
    const bf16* __restrict__ bias, bf16* __restrict__ C,
    int N, int K, int is_bf16, int row0, int col0)
{
  __shared__ __align__(16) bf16 lA[128 * 32];
  __shared__ __align__(16) bf16 lB[BN * 32];
  constexpr int NJ = BN / 32;

  const int tid  = threadIdx.x;
  const int wave = tid >> 6;
  const int lane = tid & 63;
  const int wr0  = (wave >> 1) * 64;
  const int wc0  = (wave & 1) * (BN / 2);

  f32x4v acc[4][NJ];
#pragma unroll
  for (int i = 0; i < 4; i++)
#pragma unroll
    for (int j = 0; j < NJ; j++) acc[i][j] = (f32x4v){0.f, 0.f, 0.f, 0.f};

  // A staging: row = wave*16 + lane/4 (+64 second vector), kchunk=(lane&3)*8
  const int srow = wave * 16 + (lane >> 2);
  const int skc  = (lane & 3) * 8;
  const bf16* Ag = A + (size_t)(row0 + srow) * K + skc;
  bf16* lAp = lA + tid * 8;
  // B staging: BN=128 mirrors A (2 vectors); BN=64: row=tid/4 (1 vector)
  size_t bidx;
  if constexpr (BN == 128) bidx = woff + (size_t)(col0 + srow) * K + skc;
  else                     bidx = woff + (size_t)(col0 + (tid >> 2)) * K + (tid & 3) * 8;
  bf16* lBp = lB + tid * 8;

  const int fr = lane & 15;
  const int q8 = (lane >> 4) * 8;

  bf16x8v va0, va1, nb0, nb1;
  f32x4v  g0, g1, g2, g3;

  auto issue = [&](int k0) {
    va0 = *reinterpret_cast<const bf16x8v*>(Ag + k0);
    va1 = *reinterpret_cast<const bf16x8v*>(Ag + (size_t)64 * K + k0);
    if (is_bf16) {
      const bf16* Wb = (const bf16*)Wp + bidx + k0;
      nb0 = *reinterpret_cast<const bf16x8v*>(Wb);
      if constexpr (BN == 128)
        nb1 = *reinterpret_cast<const bf16x8v*>(Wb + (size_t)64 * K);
    } else {
      const float* Wf = (const float*)Wp + bidx + k0;
      g0 = *reinterpret_cast<const f32x4v*>(Wf);
      g1 = *reinterpret_cast<const f32x4v*>(Wf + 4);
      if constexpr (BN == 128) {
        g2 = *reinterpret_cast<const f32x4v*>(Wf + (size_t)64 * K);
        g3 = *reinterpret_cast<const f32x4v*>(Wf + (size_t)64 * K + 4);
      }
    }
  };

  auto commit = [&]() {
    bf16x8v w0, w1;
    if (is_bf16) {
      w0 = nb0;
      if constexpr (BN == 128) w1 = nb1;
    } else {
#pragma unroll
      for (int j = 0; j < 4; j++) { w0[j] = (__bf16)g0[j]; w0[j + 4] = (__bf16)g1[j]; }
      if constexpr (BN == 128) {
#pragma unroll
        for (int j = 0; j < 4; j++) { w1[j] = (__bf16)g2[j]; w1[j + 4] = (__bf16)g3[j]; }
      }
    }
    *reinterpret_cast<bf16x8v*>(lAp)        = va0;
    *reinterpret_cast<bf16x8v*>(lAp + 2048) = va1;
    *reinterpret_cast<bf16x8v*>(lBp)        = w0;
    if constexpr (BN == 128) *reinterpret_cast<bf16x8v*>(lBp + 2048) = w1;
  };

  issue(0);
  for (int k0 = 0; k0 < K; k0 += 32) {
    __syncthreads();                         // WAR: previous iter's readers done
    commit();                                // vmcnt wait lands here
    __syncthreads();                         // staging visible
    if (k0 + 32 < K) issue(k0 + 32);         // prefetch: hides under MFMA below

    bf16x8v af[4], bw[NJ];
#pragma unroll
    for (int i = 0; i < 4; i++)
      af[i] = *reinterpret_cast<const bf16x8v*>(&lA[(wr0 + i * 16 + fr) * 32 + q8]);
#pragma unroll
    for (int j = 0; j < NJ; j++)
      bw[j] = *reinterpret_cast<const bf16x8v*>(&lB[(wc0 + j * 16 + fr) * 32 + q8]);
#pragma unroll
    for (int i = 0; i < 4; i++)
#pragma unroll
      for (int j = 0; j < NJ; j++)
        acc[i][j] = __builtin_amdgcn_mfma_f32_16x16x32_bf16(af[i], bw[j], acc[i][j], 0, 0, 0);
  }

  const int quad = (lane >> 4) * 4;
#pragma unroll
  for (int j = 0; j < NJ; j++) {
    const int col = col0 + wc0 + j * 16 + fr;
    const float bvf = (float)bias[col];
#pragma unroll
    for (int i = 0; i < 4; i++) {
      const int r0 = row0 + wr0 + i * 16 + quad;
#pragma unroll
      for (int r = 0; r < 4; r++) {
        float v = acc[i][j][r] + bvf;
        if (EPI == 1) v = fmaxf(v, 0.f);
        C[(size_t)(r0 + r) * N + col] = (bf16)v;
      }
    }
  }
}

template<int EPI, int BN>
__global__ __launch_bounds__(256) void gemm_nt(
    const bf16* __restrict__ A, const void* __restrict__ Wp, size_t woff,
    const bf16* __restrict__ bias, bf16* __restrict__ C,
    int M, int N, int K, const int* __restrict__ dflag)
{
  gemm_core<EPI, BN>(A, Wp, woff, bias, C, N, K, *dflag,
                     blockIdx.x * 128, blockIdx.y * BN);
}

// Fused Q/K/V projection: one N=3072 launch (768 blocks = 3/CU vs 3x256=1/CU).
// Each 128-col block lies entirely inside one of the three 1024-col tensors
// (128 | 1024), so W / bias / C are selected per-block (uniform branch).
__global__ __launch_bounds__(256) void gemm_qkv(
    const bf16* __restrict__ A,
    const void* __restrict__ Wq, const void* __restrict__ Wk, const void* __restrict__ Wv,
    size_t woff,
    const bf16* __restrict__ bq, const bf16* __restrict__ bk, const bf16* __restrict__ bv,
    bf16* __restrict__ Cq, bf16* __restrict__ Ck, bf16* __restrict__ Cv,
    int K, const int* __restrict__ dflag)
{
  const int cg = blockIdx.y * 128;
  const int t  = cg >> 10;
  const void* W    = (t == 0) ? Wq : (t == 1) ? Wk : Wv;
  const bf16* bias = (t == 0) ? bq : (t == 1) ? bk : bv;
  bf16*       C    = (t == 0) ? Cq : (t == 1) ? Ck : Cv;
  gemm_core<0, 128>(A, W, woff, bias, C, 1024, K, *dflag,
                    blockIdx.x * 128, cg & 1023);
}

// ---------------------------------------------------------------------------
// Band-sparse attention, MFMA version. One block = 32 query rows of one
// (b,h); band span <= 124, padded to 128 keys (K/V zero-filled past L).
// MASKING: both |s-t|<=WBAND AND c<L are required. The c<L check is NOT
// redundant at the tail blocks: when thi clamps to SEQL-1, phantom columns
// c>=L have t=tlo+c numerically within the band of late rows (e.g. s=2047,
// t=2048) and their zero-filled K gives score 0, which would otherwise
// inflate the softmax denominator (round-1 failure, absmax 0.54).
//
// QK^T: M=32(q) N=128(key) K=64(d), 16 tiles of 16x16x32 (2 k-steps), 4 per
// wave. PV: M=32(q) N=64(d) K=128(key), needs B[n=d][k=key] = V^T, so V is
// staged transposed. All LDS tiles XOR-swizzled (elem ^= (row&7)<<3; f32
// score tile (row&7)<<2) so ds_read_b128 fragment reads sit at the 2-way /
// bandwidth floor (G4: row-major [*][64/128] tiles are otherwise 16-32-way).
// O may alias Q: the block's Q reads are staged to LDS before any O write,
// and blocks touch disjoint (rows x head-cols) slices.
// ---------------------------------------------------------------------------
#define SKI(t, d)  ((((t) * 64) + (d)) ^ (((t) & 7) << 3))   // sQf / sKf (64-wide)
#define SVI(d, t)  ((((d) * 128) + (t)) ^ (((d) & 7) << 3))  // sVtf (128-wide)
#define SPI(q, c)  ((((q) * 128) + (c)) ^ (((q) & 7) << 3))  // sPf
#define SSI(q, c)  ((((q) * 128) + (c)) ^ (((q) & 7) << 2))  // sSf (f32)

__global__ __launch_bounds__(256) void attn_band(
    const bf16* __restrict__ Q, const bf16* __restrict__ Kp,
    const bf16* __restrict__ Vp, bf16* __restrict__ O)
{
  const int sblk = blockIdx.x;
  const int bh   = blockIdx.y;
  const int b    = bh >> 4;
  const int h    = bh & 15;
  const int s0   = sblk * 32;
  int tlo = s0 - WBAND;       if (tlo < 0) tlo = 0;
  int thi = s0 + 31 + WBAND;  if (thi > SEQL - 1) thi = SEQL - 1;
  const int L = thi - tlo + 1;           // 78..124

  __shared__ __align__(16) bf16  sQf[32 * 64];
  __shared__ __align__(16) bf16  sKf[128 * 64];
  __shared__ __align__(16) bf16  sVtf[64 * 128];
  __shared__ __align__(16) float sSf[32 * 128];
  __shared__ __align__(16) bf16  sPf[32 * 128];
  __shared__ float red1[32][8];
  __shared__ float red2[32][8];
  __shared__ float sInv[32];

  const int tid  = threadIdx.x;
  const int wave = tid >> 6;
  const int lane = tid & 63;
  const size_t base = ((size_t)b * SEQL) * EMBED + (size_t)h * HD;

  bf16x8v vz;
#pragma unroll
  for (int j = 0; j < 8; j++) vz[j] = (__bf16)0.f;

  // --- stage Q (32x64): one bf16x8 per thread
  {
    const int sl = tid >> 3, d0 = (tid & 7) * 8;
    *reinterpret_cast<bf16x8v*>(&sQf[SKI(sl, d0)]) =
        *reinterpret_cast<const bf16x8v*>(&Q[base + (size_t)(s0 + sl) * EMBED + d0]);
  }
  // --- stage K (128x64), zero-padded rows >= L
  for (int i = tid; i < 128 * 8; i += 256) {
    const int tl = i >> 3, d0 = (i & 7) * 8;
    bf16x8v v = vz;
    if (tl < L)
      v = *reinterpret_cast<const bf16x8v*>(&Kp[base + (size_t)(tlo + tl) * EMBED + d0]);
    *reinterpret_cast<bf16x8v*>(&sKf[SKI(tl, d0)]) = v;
  }
  // --- stage V transposed (d-major rows): lane-consecutive tl keeps the
  // scalar LDS column-writes 2-way (conflict floor); global is 16B/lane.
  for (int i = tid; i < 128 * 8; i += 256) {
    const int tl = i & 127, d0 = ((i >> 7) & 7) * 8;
    bf16x8v v = vz;
    if (tl < L)
      v = *reinterpret_cast<const bf16x8v*>(&Vp[base + (size_t)(tlo + tl) * EMBED + d0]);
#pragma unroll
    for (int j = 0; j < 8; j++)
      sVtf[SVI(d0 + j, tl)] = reinterpret_cast<const bf16*>(&v)[j];
  }
  __syncthreads();

  const int fr   = lane & 15;
  const int q8   = (lane >> 4) * 8;
  const int quad = (lane >> 4) * 4;

  // --- QK^T: wave w owns n-tiles {2w, 2w+1} x m-tiles {0,1}
  {
    f32x4v acc[2][2];
#pragma unroll
    for (int mi = 0; mi < 2; mi++)
#pragma unroll
      for (int nj = 0; nj < 2; nj++) acc[mi][nj] = (f32x4v){0.f, 0.f, 0.f, 0.f};
#pragma unroll
    for (int ks = 0; ks < 2; ks++) {
      bf16x8v a0 = *reinterpret_cast<const bf16x8v*>(&sQf[SKI(fr,      ks * 32 + q8)]);
      bf16x8v a1 = *reinterpret_cast<const bf16x8v*>(&sQf[SKI(16 + fr, ks * 32 + q8)]);
      bf16x8v b0 = *reinterpret_cast<const bf16x8v*>(&sKf[SKI((wave * 2    ) * 16 + fr, ks * 32 + q8)]);
      bf16x8v b1 = *reinterpret_cast<const bf16x8v*>(&sKf[SKI((wave * 2 + 1) * 16 + fr, ks * 32 + q8)]);
      acc[0][0] = __builtin_amdgcn_mfma_f32_16x16x32_bf16(a0, b0, acc[0][0], 0, 0, 0);
      acc[0][1] = __builtin_amdgcn_mfma_f32_16x16x32_bf16(a0, b1, acc[0][1], 0, 0, 0);
      acc[1][0] = __builtin_amdgcn_mfma_f32_16x16x32_bf16(a1, b0, acc[1][0], 0, 0, 0);
      acc[1][1] = __builtin_amdgcn_mfma_f32_16x16x32_bf16(a1, b1, acc[1][1], 0, 0, 0);
    }
    // mask + scale + store scores; needs BOTH the band check and c < L
    // (phantom tail columns pass the band check at clamped-thi blocks)
#pragma unroll
    for (int nj = 0; nj < 2; nj++) {
      const int c = (wave * 2 + nj) * 16 + fr;
      const int t = tlo + c;
      const bool cvalid = (c < L);
#pragma unroll
      for (int mi = 0; mi < 2; mi++) {
#pragma unroll
        for (int r = 0; r < 4; r++) {
          const int row = mi * 16 + quad + r;
          int dd = (s0 + row) - t; if (dd < 0) dd = -dd;
          sSf[SSI(row, c)] = (cvalid && dd <= WBAND) ? acc[mi][nj][r] * 0.125f
                                                     : -1e30f;
        }
      }
    }
  }
  __syncthreads();

  // --- softmax over 128 cols, 8 partitions per row (row = tid&31)
  const int sl   = tid & 31;
  const int part = tid >> 5;
  float pmax = -1e30f;
#pragma unroll
  for (int k = 0; k < 16; k++) pmax = fmaxf(pmax, sSf[SSI(sl, part + 8 * k)]);
  red1[sl][part] = pmax;
  __syncthreads();
  float rmax = red1[sl][0];
#pragma unroll
  for (int p = 1; p < 8; p++) rmax = fmaxf(rmax, red1[sl][p]);

  float psum = 0.f;
#pragma unroll
  for (int k = 0; k < 16; k++) {
    const int c = part + 8 * k;
    float e = __expf(sSf[SSI(sl, c)] - rmax);   // masked/padded -> exactly 0
    sPf[SPI(sl, c)] = (bf16)e;
    psum += e;
  }
  red2[sl][part] = psum;
  __syncthreads();
  float rsum = 0.f;
#pragma unroll
  for (int p = 0; p < 8; p++) rsum += red2[sl][p];
  if (part == 0) sInv[sl] = 1.f / rsum;
  __syncthreads();                              // sPf + sInv ready

  // --- PV: O[32,64] = P[32,128] @ V. wave w: m-tile w>>1, n-tiles (w&1)*2+{0,1}
  {
    const int mi = wave >> 1;
    const int nb = (wave & 1) * 2;
    f32x4v acc[2];
    acc[0] = (f32x4v){0.f, 0.f, 0.f, 0.f};
    acc[1] = (f32x4v){0.f, 0.f, 0.f, 0.f};
#pragma unroll
    for (int ks = 0; ks < 4; ks++) {
      bf16x8v a  = *reinterpret_cast<const bf16x8v*>(&sPf[SPI(mi * 16 + fr, ks * 32 + q8)]);
      bf16x8v b0 = *reinterpret_cast<const bf16x8v*>(&sVtf[SVI((nb    ) * 16 + fr, ks * 32 + q8)]);
      bf16x8v b1 = *reinterpret_cast<const bf16x8v*>(&sVtf[SVI((nb + 1) * 16 + fr, ks * 32 + q8)]);
      acc[0] = __builtin_amdgcn_mfma_f32_16x16x32_bf16(a, b0, acc[0], 0, 0, 0);
      acc[1] = __builtin_amdgcn_mfma_f32_16x16x32_bf16(a, b1, acc[1], 0, 0, 0);
    }
#pragma unroll
    for (int nj = 0; nj < 2; nj++) {
      const int d = (nb + nj) * 16 + fr;
#pragma unroll
      for (int r = 0; r < 4; r++) {
        const int row = mi * 16 + quad + r;
        O[base + (size_t)(s0 + row) * EMBED + d] = (bf16)(acc[nj][r] * sInv[row]);
      }
    }
  }
}

// ---------------------------------------------------------------------------
// Fused residual add + LayerNorm. fp32 residual in/out (xin may == xf_out),
// bf16 GEMM-branch input y, bf16 activation out. Optional final output:
// dtype keyed off dflag (fp32 world -> float*, bf16 world -> bf16*).
// ---------------------------------------------------------------------------
__global__ __launch_bounds__(256) void resid_ln(
    const float* xin, const bf16* __restrict__ y,
    const bf16* __restrict__ g, const bf16* __restrict__ be,
    float* xf_out, bf16* __restrict__ xb_out,
    void* __restrict__ final_out, const int* __restrict__ dflag)
{
  __shared__ float red1[4];
  __shared__ float red2[4];
  const int row = blockIdx.x;
  const int tid = threadIdx.x;
  const size_t base = (size_t)row * EMBED + (size_t)tid * 4;

  f32x4v  xv = *reinterpret_cast<const f32x4v*>(xin + base);
  bf16x4v yv = *reinterpret_cast<const bf16x4v*>(y + base);
  float v[4];
#pragma unroll
  for (int j = 0; j < 4; j++) v[j] = xv[j] + (float)yv[j];

  float s = v[0] + v[1] + v[2] + v[3];
#pragma unroll
  for (int off = 32; off > 0; off >>= 1) s += __shfl_down(s, off, 64);
  if ((tid & 63) == 0) red1[tid >> 6] = s;
  __syncthreads();
  const float mu = (red1[0] + red1[1] + red1[2] + red1[3]) * (1.f / EMBED);

  float sq = 0.f;
#pragma unroll
  for (int j = 0; j < 4; j++) { const float d = v[j] - mu; sq += d * d; }
#pragma unroll
  for (int off = 32; off > 0; off >>= 1) sq += __shfl_down(sq, off, 64);
  if ((tid & 63) == 0) red2[tid >> 6] = sq;
  __syncthreads();
  const float rstd = rsqrtf((red2[0] + red2[1] + red2[2] + red2[3]) * (1.f / EMBED) + LN_EPS);

  bf16x4v gv = *reinterpret_cast<const bf16x4v*>(g + (size_t)tid * 4);
  bf16x4v bv = *reinterpret_cast<const bf16x4v*>(be + (size_t)tid * 4);
  f32x4v of;
  bf16x4v ov;
#pragma unroll
  for (int j = 0; j < 4; j++) {
    of[j] = (v[j] - mu) * rstd * (float)gv[j] + (float)bv[j];
    ov[j] = (__bf16)of[j];
  }
  *reinterpret_cast<f32x4v*>(xf_out + base) = of;
  *reinterpret_cast<bf16x4v*>(xb_out + base) = ov;
  if (final_out) {
    if (*dflag)
      *reinterpret_cast<bf16x4v*>((bf16*)final_out + base) = ov;
    else
      *reinterpret_cast<f32x4v*>((float*)final_out + base) = of;
  }
}

// ---------------------------------------------------------------------------
// ws layout (65 MB peak, liveness-verified):
//  [0,4K) flag | [4K,~112K) bf16 param copies
//  [ 1,17) xf fp32 residual | [17,25) xb bf16 activation
//  [25,33) q (=ao alias)    | [33,41) kk | [41,49) vv
//  [25,57) hh 32MB (aliases q/kk/vv + free [49,57); all dead at FF1)
//  [57,65) y bf16 GEMM out  (disjoint from hh: FF2 reads hh, writes y)
// ---------------------------------------------------------------------------
extern "C" void kernel_launch(void* const* d_in, const int* in_sizes, int n_in,
                              void* d_out, int out_size, void* d_ws, size_t ws_size,
                              hipStream_t stream)
{
  char* ws = (char*)d_ws;
  const size_t MB = 1024 * 1024;
  int*   flag = (int*)ws;
  bf16*  pp   = (bf16*)(ws + 4096);
  float* xf   = (float*)(ws + 1 * MB);
  bf16*  xb   = (bf16*)(ws + 17 * MB);
  bf16*  q    = (bf16*)(ws + 25 * MB);
  bf16*  kk   = (bf16*)(ws + 33 * MB);
  bf16*  vv   = (bf16*)(ws + 41 * MB);
  bf16*  ao   = q;
  bf16*  hh   = (bf16*)(ws + 25 * MB);     // 32 MB
  bf16*  y    = (bf16*)(ws + 57 * MB);

  // bf16 param-copy element offsets within pp
  bf16* pbq = pp;            bf16* pbk = pp + 4096;  bf16* pbv = pp + 8192;
  bf16* pbo = pp + 12288;    bf16* pb1 = pp + 16384; bf16* pb2 = pp + 32768;
  bf16* pg1 = pp + 36864;    bf16* pe1 = pp + 40960;
  bf16* pg2 = pp + 45056;    bf16* pe2 = pp + 49152;

  detect_dtype<<<1, 256, 0, stream>>>((const unsigned int*)d_in[0], flag);

  cast_param<<<16, 256, 0, stream>>>(d_in[2],  pbq, 4096,  flag);
  cast_param<<<16, 256, 0, stream>>>(d_in[4],  pbk, 4096,  flag);
  cast_param<<<16, 256, 0, stream>>>(d_in[6],  pbv, 4096,  flag);
  cast_param<<<16, 256, 0, stream>>>(d_in[8],  pbo, 4096,  flag);
  cast_param<<<64, 256, 0, stream>>>(d_in[10], pb1, 16384, flag);
  cast_param<<<16, 256, 0, stream>>>(d_in[12], pb2, 4096,  flag);
  cast_param<<<16, 256, 0, stream>>>(d_in[13], pg1, 4096,  flag);
  cast_param<<<16, 256, 0, stream>>>(d_in[14], pe1, 4096,  flag);
  cast_param<<<16, 256, 0, stream>>>(d_in[15], pg2, 4096,  flag);
  cast_param<<<16, 256, 0, stream>>>(d_in[16], pe2, 4096,  flag);

  cast_in<<<dim3((NTOK * EMBED) / 256), 256, 0, stream>>>(
      d_in[0], xf, xb, NTOK * EMBED, flag);

  for (int l = 0; l < 4; l++) {
    const size_t wEE = (size_t)l * EMBED * EMBED;
    const size_t wFE = (size_t)l * FF_DIM * EMBED;

    gemm_qkv<<<dim3(32, 24), 256, 0, stream>>>(
        xb, d_in[1], d_in[3], d_in[5], wEE,
        pbq + l * 1024, pbk + l * 1024, pbv + l * 1024,
        q, kk, vv, EMBED, flag);
    attn_band<<<dim3(SEQL / 32, 32), 256, 0, stream>>>(q, kk, vv, ao);
    gemm_nt<0, 64><<<dim3(32, 16), 256, 0, stream>>>(
        ao, d_in[7], wEE, pbo + l * 1024, y, NTOK, EMBED, EMBED, flag);
    resid_ln<<<dim3(NTOK), 256, 0, stream>>>(xf, y, pg1 + l * 1024, pe1 + l * 1024, xf, xb, nullptr, flag);
    gemm_nt<1, 128><<<dim3(32, 32), 256, 0, stream>>>(
        xb, d_in[9], wFE, pb1 + l * 4096, hh, NTOK, FF_DIM, EMBED, flag);
    gemm_nt<0, 64><<<dim3(32, 16), 256, 0, stream>>>(
        hh, d_in[11], wFE, pb2 + l * 1024, y, NTOK, EMBED, FF_DIM, flag);
    resid_ln<<<dim3(NTOK), 256, 0, stream>>>(xf, y, pg2 + l * 1024, pe2 + l * 1024, xf, xb,
                                             l == 3 ? d_out : nullptr, flag);
  }
}